// Round 1
// baseline (75.888 us; speedup 1.0000x reference)
//
#include <hip/hip_runtime.h>
#include <math.h>

// Problem constants (from reference)
constexpr int Hr = 64;
constexpr int Wr = 2048;
constexpr int Hb = 512;
constexpr int Wb = 512;
constexpr int B  = 4;
constexpr int C  = 64;
constexpr int BC = B * C;            // 256 channels
constexpr int NPIX = Hb * Wb;        // 262144 pixels
constexpr double R_MAX  = 50.0;
constexpr double TWO_PI = 6.283185307179586476925286766559;

// py = (gy+1)/2*(Hr-1) with gy = VERT_ROW/Hr*2-1 = 0  ->  py = 31.5
// => y0 = 31, y1 = 32, wy = 0.5 exactly.

__global__ __launch_bounds__(256) void rv2bev_kernel(
    const float* __restrict__ rv,   // [B][C][Hr][Wr]
    float* __restrict__ out)        // [B][C][Hb][Wb]
{
    const int n = blockIdx.x * 256 + threadIdx.x;   // pixel index, < NPIX
    const int yy = n >> 9;          // n / Wb  (Wb = 512)
    const int xx = n & 511;         // n % Wb

    // Coordinate math in double to match numpy's float64 -> astype(float32).
    const double y = ((double)yy - (double)(Hb / 2) + 0.5) * R_MAX / ((double)(Hb / 2) - 0.5);
    const double x = ((double)xx - (double)(Wb / 2) + 0.5) * R_MAX / ((double)(Wb / 2) - 0.5);
    double phi = fmod(atan2(y, x) + TWO_PI, TWO_PI);
    const double col = (double)(Wr - 1) - phi / TWO_PI * (double)(Wr - 1);
    const double gx  = col / (double)Wr * 2.0 - 1.0;
    const float  px  = (float)((gx + 1.0) / 2.0 * (double)(Wr - 1));

    // grid_sample x-interp (float32, matching jax)
    const int   x0 = (int)floorf(px);       // in [0, 2046]
    const float wx = px - (float)x0;
    const float w0 = 1.0f - wx;

    // base pointer to row 31 of channel 0; per-channel stride Hr*Wr
    const float* __restrict__ p = rv + (size_t)31 * Wr;
    float* __restrict__ op = out + n;

    #pragma unroll 4
    for (int bc = 0; bc < BC; ++bc) {
        const float* __restrict__ base = p + (size_t)bc * (Hr * Wr);
        const float a0 = base[x0];
        const float a1 = base[x0 + 1];
        const float b0 = base[Wr + x0];
        const float b1 = base[Wr + x0 + 1];
        const float r0 = a0 * 0.5f + b0 * 0.5f;   // row interp, wy = 0.5
        const float r1 = a1 * 0.5f + b1 * 0.5f;
        const float s  = r0 * w0 + r1 * wx;
        __builtin_nontemporal_store(s, op + (size_t)bc * NPIX);
    }
}

extern "C" void kernel_launch(void* const* d_in, const int* in_sizes, int n_in,
                              void* d_out, int out_size, void* d_ws, size_t ws_size,
                              hipStream_t stream) {
    const float* rv_feat = (const float*)d_in[0];
    // d_in[1] (ref_bev) is unused by the reference computation.
    float* out = (float*)d_out;

    dim3 grid(NPIX / 256);
    dim3 block(256);
    rv2bev_kernel<<<grid, block, 0, stream>>>(rv_feat, out);
}

// Round 3
// 59.018 us; speedup vs baseline: 1.2859x; 1.2859x over previous
//
#include <hip/hip_runtime.h>
#include <math.h>

// Problem constants (from reference)
constexpr int Hr = 64;
constexpr int Wr = 2048;
constexpr int Hb = 512;
constexpr int Wb = 512;
constexpr int B  = 4;
constexpr int C  = 64;
constexpr int BC = B * C;            // 256 channels
constexpr int NPIX = Hb * Wb;        // 262144 pixels
constexpr double R_MAX  = 50.0;
constexpr double TWO_PI = 6.283185307179586476925286766559;

constexpr int PPB = 8192;            // pixels per block in sample kernel

typedef float f32x4 __attribute__((ext_vector_type(4)));   // native vector for nontemporal builtins

// py = 31.5 exactly -> y0=31, y1=32, wy=0.5.
// rowavg[bc][x] = rv[bc][31][x]*0.5 + rv[bc][32][x]*0.5  (matches ref's
// row = r31*(1-wy) + r32*wy bitwise: *0.5 is exact, one rounding on the add).

// ---------------------------------------------------------------------------
// Kernel A: precompute rowavg (2 MB) and px (1 MB) into workspace.
// Blocks [0,512): rowavg as float4 (131072 float4 elems).
// Blocks [512,1536): px via double-precision coordinate math (matches numpy).
// ---------------------------------------------------------------------------
__global__ __launch_bounds__(256) void prep_kernel(
    const float* __restrict__ rv,      // [B][C][Hr][Wr]
    float* __restrict__ rowavg,        // [BC][Wr]
    float* __restrict__ pxbuf)         // [NPIX]
{
    const int b   = blockIdx.x;
    const int tid = threadIdx.x;

    if (b < 512) {
        const int i  = b * 256 + tid;      // float4 index, < 131072
        const int bc = i >> 9;             // 512 float4 per channel
        const int xi = i & 511;
        const f32x4* r31 = (const f32x4*)(rv + (size_t)bc * (Hr * Wr) + (size_t)31 * Wr);
        const f32x4* r32 = (const f32x4*)(rv + (size_t)bc * (Hr * Wr) + (size_t)32 * Wr);
        const f32x4 a = r31[xi];
        const f32x4 c = r32[xi];
        f32x4 o;
        o.x = a.x * 0.5f + c.x * 0.5f;
        o.y = a.y * 0.5f + c.y * 0.5f;
        o.z = a.z * 0.5f + c.z * 0.5f;
        o.w = a.w * 0.5f + c.w * 0.5f;
        ((f32x4*)rowavg)[i] = o;
    } else {
        const int n  = (b - 512) * 256 + tid;   // pixel index, < NPIX
        const int yy = n >> 9;
        const int xx = n & 511;
        const double y = ((double)yy - (double)(Hb / 2) + 0.5) * R_MAX / ((double)(Hb / 2) - 0.5);
        const double x = ((double)xx - (double)(Wb / 2) + 0.5) * R_MAX / ((double)(Wb / 2) - 0.5);
        const double phi = fmod(atan2(y, x) + TWO_PI, TWO_PI);
        const double col = (double)(Wr - 1) - phi / TWO_PI * (double)(Wr - 1);
        const double gx  = col / (double)Wr * 2.0 - 1.0;
        pxbuf[n] = (float)((gx + 1.0) / 2.0 * (double)(Wr - 1));
    }
}

// ---------------------------------------------------------------------------
// Kernel B: one block per (channel, 8192-pixel tile). Stage the channel's
// 8 KB averaged row in LDS; gather from LDS; coalesced float4 px reads and
// nontemporal float4 output stores.
// ---------------------------------------------------------------------------
__global__ __launch_bounds__(256) void sample_kernel(
    const float* __restrict__ rowavg,  // [BC][Wr]
    const float* __restrict__ pxbuf,   // [NPIX]
    float* __restrict__ out)           // [BC][NPIX]
{
    __shared__ float row[Wr];          // 8 KB

    const int bc   = blockIdx.y;
    const int tile = blockIdx.x;
    const int tid  = threadIdx.x;

    // Stage averaged row: 512 float4, 256 threads -> 2 each, coalesced.
    {
        const f32x4* src = (const f32x4*)(rowavg + (size_t)bc * Wr);
        f32x4* dst = (f32x4*)row;
        dst[tid]       = src[tid];
        dst[tid + 256] = src[tid + 256];
    }
    __syncthreads();

    const f32x4* px4  = (const f32x4*)(pxbuf + (size_t)tile * PPB);
    f32x4*       out4 = (f32x4*)(out + (size_t)bc * NPIX + (size_t)tile * PPB);

    #pragma unroll
    for (int k = 0; k < 8; ++k) {
        const int idx = tid + k * 256;      // float4 index within tile (PPB/4 = 2048)
        const f32x4 p = px4[idx];
        f32x4 r;
        {
            const int x0 = (int)floorf(p.x); const float wx = p.x - (float)x0;
            r.x = row[x0] * (1.0f - wx) + row[x0 + 1] * wx;
        }
        {
            const int x0 = (int)floorf(p.y); const float wx = p.y - (float)x0;
            r.y = row[x0] * (1.0f - wx) + row[x0 + 1] * wx;
        }
        {
            const int x0 = (int)floorf(p.z); const float wx = p.z - (float)x0;
            r.z = row[x0] * (1.0f - wx) + row[x0 + 1] * wx;
        }
        {
            const int x0 = (int)floorf(p.w); const float wx = p.w - (float)x0;
            r.w = row[x0] * (1.0f - wx) + row[x0 + 1] * wx;
        }
        __builtin_nontemporal_store(r, out4 + idx);
    }
}

extern "C" void kernel_launch(void* const* d_in, const int* in_sizes, int n_in,
                              void* d_out, int out_size, void* d_ws, size_t ws_size,
                              hipStream_t stream) {
    const float* rv_feat = (const float*)d_in[0];
    // d_in[1] (ref_bev) is unused by the reference computation.
    float* out = (float*)d_out;

    float* rowavg = (float*)d_ws;                 // BC*Wr floats   = 2 MB
    float* pxbuf  = rowavg + (size_t)BC * Wr;     // NPIX floats    = 1 MB
    // total workspace use: 3 MB

    prep_kernel<<<dim3(512 + NPIX / 256), dim3(256), 0, stream>>>(rv_feat, rowavg, pxbuf);
    sample_kernel<<<dim3(NPIX / PPB, BC), dim3(256), 0, stream>>>(rowavg, pxbuf, out);
}

// Round 4
// 57.130 us; speedup vs baseline: 1.3283x; 1.0330x over previous
//
#include <hip/hip_runtime.h>
#include <math.h>

// Problem constants (from reference)
constexpr int Hr = 64;
constexpr int Wr = 2048;
constexpr int Hb = 512;
constexpr int Wb = 512;
constexpr int B  = 4;
constexpr int C  = 64;
constexpr int BC = B * C;            // 256 channels
constexpr int NPIX = Hb * Wb;        // 262144 pixels

constexpr int T = 8192;              // pixels per tile (per block)
constexpr int G = 8;                 // channels per block
constexpr int NTILE = NPIX / T;      // 32
constexpr int NCG   = BC / G;        // 32

typedef float f32x4 __attribute__((ext_vector_type(4)));

// py = 31.5 exactly -> rows 31,32 with wy = 0.5.
// px math done in float32: bilinear interp is continuous in px, so the
// ~4e-4 px error vs numpy's float64 path gives value error ~2e-3 << 0.066
// threshold. The phi-wrap discontinuity is 1.96e-3 rad from the nearest
// sample point; float atan2f error (~1e-7 rad) cannot cross it.

__global__ __launch_bounds__(256) void rv2bev_fused(
    const float* __restrict__ rv,    // [B][C][Hr][Wr]
    float* __restrict__ out)         // [B][C][Hb][Wb]
{
    __shared__ float rowbuf[2][Wr];  // 2 x 8 KB, double-buffered averaged row

    const int tile = blockIdx.x;     // 0..31
    const int cg   = blockIdx.y;     // 0..31
    const int tid  = threadIdx.x;

    // ---- per-block px computation: 32 pixels/thread, kept in registers ----
    int   x0[32];
    float wx[32];
    {
        const float cs = 50.0f / 255.5f;                    // R_MAX / (Hb/2 - 0.5)
        const float c1 = 2047.0f / 6.28318530717958647692f; // (Wr-1)/2pi
        const float c2 = 2047.0f / 2048.0f;                 // (Wr-1)/Wr
        #pragma unroll
        for (int k = 0; k < 8; ++k) {
            #pragma unroll
            for (int j = 0; j < 4; ++j) {
                const int n  = tile * T + (tid + k * 256) * 4 + j;  // global pixel
                const float y = ((float)(n >> 9)  - 255.5f) * cs;
                const float x = ((float)(n & 511) - 255.5f) * cs;
                float phi = atan2f(y, x);
                phi = (phi < 0.0f) ? phi + 6.28318530717958647692f : phi;
                // px = (col/Wr*2-1+1)/2*(Wr-1) = col*(Wr-1)/Wr, col = 2047 - phi/2pi*2047
                const float px = (2047.0f - phi * c1) * c2;   // in (0, 2046.01)
                const float fx = floorf(px);
                x0[k * 4 + j] = (int)fx;                      // <= 2046
                wx[k * 4 + j] = px - fx;
            }
        }
    }

    // base of row 31, channel cg*G
    const float* rvb = rv + (size_t)(cg * G) * (Hr * Wr) + (size_t)31 * Wr;

    f32x4 sa0, sa1, sb0, sb1;        // staged rows for next channel

    // ---- prologue: stage channel 0 into rowbuf[0] ----
    {
        const f32x4* r31 = (const f32x4*)rvb;
        const f32x4* r32 = (const f32x4*)(rvb + Wr);
        sa0 = r31[tid]; sa1 = r31[tid + 256];
        sb0 = r32[tid]; sb1 = r32[tid + 256];
        f32x4* dst = (f32x4*)rowbuf[0];
        dst[tid]       = sa0 * 0.5f + sb0 * 0.5f;
        dst[tid + 256] = sa1 * 0.5f + sb1 * 0.5f;
    }

    for (int c = 0; c < G; ++c) {
        // T14 issue-early: launch next channel's global loads before the barrier
        if (c + 1 < G) {
            const float* chb = rvb + (size_t)(c + 1) * (Hr * Wr);
            const f32x4* r31 = (const f32x4*)chb;
            const f32x4* r32 = (const f32x4*)(chb + Wr);
            sa0 = r31[tid]; sa1 = r31[tid + 256];
            sb0 = r32[tid]; sb1 = r32[tid + 256];
        }
        __syncthreads();             // rowbuf[c&1] staged & prior gathers done

        const float* __restrict__ row = rowbuf[c & 1];
        f32x4* out4 = (f32x4*)(out + (size_t)(cg * G + c) * NPIX + (size_t)tile * T);
        #pragma unroll
        for (int k = 0; k < 8; ++k) {
            f32x4 r;
            #pragma unroll
            for (int j = 0; j < 4; ++j) {
                const int i = k * 4 + j;
                const float w = wx[i];
                r[j] = row[x0[i]] * (1.0f - w) + row[x0[i] + 1] * w;
            }
            __builtin_nontemporal_store(r, out4 + tid + k * 256);
        }

        // write-late: LDS write of next channel after this channel's gathers
        if (c + 1 < G) {
            f32x4* dst = (f32x4*)rowbuf[(c + 1) & 1];
            dst[tid]       = sa0 * 0.5f + sb0 * 0.5f;
            dst[tid + 256] = sa1 * 0.5f + sb1 * 0.5f;
        }
    }
}

extern "C" void kernel_launch(void* const* d_in, const int* in_sizes, int n_in,
                              void* d_out, int out_size, void* d_ws, size_t ws_size,
                              hipStream_t stream) {
    const float* rv_feat = (const float*)d_in[0];
    // d_in[1] (ref_bev) is unused by the reference computation.
    float* out = (float*)d_out;

    rv2bev_fused<<<dim3(NTILE, NCG), dim3(256), 0, stream>>>(rv_feat, out);
}